// Round 5
// baseline (1287.646 us; speedup 1.0000x reference)
//
#include <hip/hip_runtime.h>
#include <hip/hip_bf16.h>

// Dims
#define BB 32
#define TT 64
#define HH 512
#define EE 512
#define VV 32000

typedef float f32x4 __attribute__((ext_vector_type(4)));
typedef __bf16 bf16x8 __attribute__((ext_vector_type(8)));
typedef unsigned short u16x8 __attribute__((ext_vector_type(8)));

static __device__ __forceinline__ unsigned short f2bf(float f) {
  unsigned int u = __builtin_bit_cast(unsigned int, f);
  u += 0x7fffu + ((u >> 16) & 1u);   // RNE; inputs are finite
  return (unsigned short)(u >> 16);
}

static __device__ __forceinline__ void bf8_to_f32(const unsigned short* p, float* f) {
  u16x8 v = *(const u16x8*)p;
#pragma unroll
  for (int i = 0; i < 8; ++i) {
    unsigned u = ((unsigned)v[i]) << 16;
    f[i] = __builtin_bit_cast(float, u);
  }
}

// ---- fp32 -> bf16 bulk convert (8 elems/thread) ----
__global__ __launch_bounds__(256) void k_cvt_bf16(const float* __restrict__ in,
                                                  unsigned short* __restrict__ out,
                                                  int n8) {
  int tid = blockIdx.x * 256 + threadIdx.x;
  if (tid >= n8) return;
  int idx = tid * 8;
  float4 a = *(const float4*)(in + idx);
  float4 b = *(const float4*)(in + idx + 4);
  u16x8 o;
  o[0] = f2bf(a.x); o[1] = f2bf(a.y); o[2] = f2bf(a.z); o[3] = f2bf(a.w);
  o[4] = f2bf(b.x); o[5] = f2bf(b.y); o[6] = f2bf(b.z); o[7] = f2bf(b.w);
  *(u16x8*)(out + idx) = o;
}

// ---- embedding gather -> bf16, layout [t*B+b][E] ----
__global__ __launch_bounds__(256) void k_emb(const int* __restrict__ seq,
                                             const float* __restrict__ emb,
                                             unsigned short* __restrict__ out) {
  int tid = blockIdx.x * 256 + threadIdx.x;   // 2048*512/8 = 131072 threads
  int idx = tid * 8;
  int m = idx >> 9;          // t*32 + b
  int e0 = idx & 511;
  int t = m >> 5, b = m & 31;
  int s = seq[b * TT + t];
  const float* src = emb + (size_t)s * EE + e0;
  float4 a = *(const float4*)(src);
  float4 c = *(const float4*)(src + 4);
  u16x8 o;
  o[0] = f2bf(a.x); o[1] = f2bf(a.y); o[2] = f2bf(a.z); o[3] = f2bf(a.w);
  o[4] = f2bf(c.x); o[5] = f2bf(c.y); o[6] = f2bf(c.z); o[7] = f2bf(c.w);
  *(u16x8*)(out + m * EE + e0) = o;
}

// ---- W_eff = W_out[:, :H] @ W_in + W_out[:, H:]  (fp32, one-time) ----
__global__ __launch_bounds__(256) void k_weff(const float* __restrict__ W_out,
                                              const float* __restrict__ W_in,
                                              float* __restrict__ W_eff) {
  __shared__ float sa[16][17], sb[16][17];
  const int t16 = threadIdx.x & 15, ty = threadIdx.x >> 4;
  const int i = blockIdx.y * 16 + ty, m = blockIdx.x * 16 + t16;
  float acc = 0.f;
  for (int k0 = 0; k0 < HH; k0 += 16) {
    sa[ty][t16] = W_out[i * 1024 + k0 + t16];
    sb[ty][t16] = W_in[(k0 + ty) * HH + m];
    __syncthreads();
#pragma unroll
    for (int kk = 0; kk < 16; ++kk) acc += sa[ty][kk] * sb[kk][t16];
    __syncthreads();
  }
  W_eff[i * HH + m] = acc + W_out[i * 1024 + HH + m];
}

__global__ __launch_bounds__(256) void k_beff(const float* __restrict__ W_out,
                                              const float* __restrict__ b_in,
                                              const float* __restrict__ b_out,
                                              float* __restrict__ b_eff) {
  int i = blockIdx.x * 256 + threadIdx.x;
  if (i >= HH) return;
  float acc = b_out[i];
  for (int k = 0; k < HH; ++k) acc += W_out[i * 1024 + k] * b_in[k];
  b_eff[i] = acc;
}

// ---- bf16 MFMA GEMM: C[M][N] = A[M][K] * Bm[N][K]^T (+col biases, +row biases) ----
// 1-D grid, XCD-chunked bijective swizzle for L2 locality.
__global__ __launch_bounds__(256) void k_gemm(const unsigned short* __restrict__ A, int lda,
                                              const unsigned short* __restrict__ Bm, int ldb,
                                              float* __restrict__ C, int ldc,
                                              const float* __restrict__ bias1,
                                              const float* __restrict__ bias2,
                                              const float* __restrict__ biasR1,
                                              const float* __restrict__ biasR2,
                                              int K, int m_panels) {
  __shared__ unsigned short As[128][40];
  __shared__ unsigned short Bs[128][40];
  const int tx = threadIdx.x;
  const int lane = tx & 63, w = tx >> 6;
  const int wrow = (w >> 1) * 64, wcol = (w & 1) * 64;
  const int l15 = lane & 15, lk = lane >> 4;
  const int nb = gridDim.x;
  const int swz = (blockIdx.x & 7) * (nb >> 3) + (blockIdx.x >> 3);
  const int m0 = (swz % m_panels) * 128, n0 = (swz / m_panels) * 128;
  f32x4 acc[4][4] = {};
  for (int k0 = 0; k0 < K; k0 += 32) {
#pragma unroll
    for (int u = 0; u < 2; ++u) {
      int c = u * 256 + tx;               // 512 16B-chunks per matrix
      int row = c >> 2, cc = (c & 3) * 8;
      *(int4*)(&As[row][cc]) = *(const int4*)(A + (size_t)(m0 + row) * lda + k0 + cc);
      *(int4*)(&Bs[row][cc]) = *(const int4*)(Bm + (size_t)(n0 + row) * ldb + k0 + cc);
    }
    __syncthreads();
    bf16x8 av[4], bv[4];
#pragma unroll
    for (int mi = 0; mi < 4; ++mi)
      av[mi] = __builtin_bit_cast(bf16x8, *(const int4*)(&As[wrow + mi * 16 + l15][lk * 8]));
#pragma unroll
    for (int ni = 0; ni < 4; ++ni)
      bv[ni] = __builtin_bit_cast(bf16x8, *(const int4*)(&Bs[wcol + ni * 16 + l15][lk * 8]));
#pragma unroll
    for (int mi = 0; mi < 4; ++mi)
#pragma unroll
      for (int ni = 0; ni < 4; ++ni)
        acc[mi][ni] = __builtin_amdgcn_mfma_f32_16x16x32_bf16(av[mi], bv[ni], acc[mi][ni], 0, 0, 0);
    __syncthreads();
  }
#pragma unroll
  for (int mi = 0; mi < 4; ++mi) {
#pragma unroll
    for (int ni = 0; ni < 4; ++ni) {
      int row = m0 + wrow + mi * 16 + lk * 4;
      int col = n0 + wcol + ni * 16 + l15;
      float bb = 0.f;
      if (bias1) bb += bias1[col];
      if (bias2) bb += bias2[col];
#pragma unroll
      for (int q = 0; q < 4; ++q) {
        float bR = 0.f;
        if (biasR1) bR += biasR1[row + q];
        if (biasR2) bR += biasR2[row + q];
        C[(size_t)(row + q) * ldc + col] = acc[mi][ni][q] + bb + bR;
      }
    }
  }
}

// ---- all-to-all fence-free grid barrier ----
// Arrival: one relaxed agent store per block. Exit: each of the 256 threads polls
// ONE flag (blockDim == gridDim == 256) -> no master hop, one MALL round-trip.
// Data is published via relaxed agent atomic stores into never-before-cached slabs,
// so no cache maintenance is needed anywhere (see round-4 design).
static __device__ __forceinline__ void gbar(unsigned* __restrict__ bar, unsigned gen) {
  __syncthreads();   // all waves drained (compiler emits vmcnt(0) before s_barrier)
  if (threadIdx.x == 0) {
    asm volatile("s_waitcnt vmcnt(0)" ::: "memory");
    __hip_atomic_store(&bar[blockIdx.x], gen, __ATOMIC_RELAXED, __HIP_MEMORY_SCOPE_AGENT);
  }
  while (__hip_atomic_load(&bar[threadIdx.x], __ATOMIC_RELAXED, __HIP_MEMORY_SCOPE_AGENT) < gen)
    __builtin_amdgcn_s_sleep(1);
  __syncthreads();
  asm volatile("" ::: "memory");   // keep data loads below the spin
}

// ---- persistent recurrence kernel: 256 blocks x 256 threads ----
// block bid owns output units i0=bid*2, i0+1. Gate weights live in LDS (fp32) for all
// 64 steps. h and feed slabs are bf16, step-unique (fresh lines -> plain loads fresh).
__global__ __launch_bounds__(256) void k_recur(
    const float* __restrict__ xprojT,   // [2048][2048]: row j, col t*32+b (incl. b_ih+b_hh)
    const float* __restrict__ W_ih,     // [2048][1024] fp32
    const float* __restrict__ W_hh,     // [2048][512] fp32
    const float* __restrict__ W_eff,    // [512][512] fp32
    const float* __restrict__ b_eff,    // [512]
    const float* __restrict__ enc_c,    // [32][512] fp32
    unsigned short* __restrict__ h_ext,    // [65][32][512] bf16; slab 0 = bf16(enc_h)
    unsigned short* __restrict__ outs_ext, // [65][32][512] bf16; slab 0 zeroed
    unsigned* __restrict__ bar)
{
  __shared__ float4 sw4[8][256];       // [W_f | W_h] rows for this block's 8 j-rows (32 KB)
  __shared__ float4 swe4[2][128];      // W_eff rows i0, i0+1 (4 KB)
  __shared__ float red[32 * 256];      // k-slice reduction scratch (32 KB)
  __shared__ float s_g[8][33];
  __shared__ float s_r[8][32];
  __shared__ float s_c[32][2];
  __shared__ float s_be[2];

  const int tx = threadIdx.x;
  const int bid = blockIdx.x;
  const int i0 = bid * 2;

  // one-time: stage gate weights [feed-half of W_ih | W_hh] for 8 j-rows
#pragma unroll
  for (int u = 0; u < 8; ++u) {
    int f4 = u * 256 + tx;
    int j = f4 >> 8, c4 = f4 & 255;
    int g = j >> 1, il = j & 1;
    int jg = g * 512 + i0 + il;
    const float* src = (c4 < 128)
        ? (W_ih + (size_t)jg * 1024 + 512 + c4 * 4)
        : (W_hh + (size_t)jg * 512 + (size_t)(c4 - 128) * 4);
    sw4[j][c4] = *(const float4*)src;
  }
  {
    int il = tx >> 7, c4 = tx & 127;
    swe4[il][c4] = *(const float4*)(W_eff + (size_t)(i0 + il) * 512 + c4 * 4);
  }
  if (tx < 64) {
    int il = tx >> 5, b = tx & 31;
    s_c[b][il] = enc_c[b * 512 + i0 + il];
  }
  if (tx < 2) s_be[tx] = b_eff[i0 + tx];

  const int p = tx & 7, s = tx >> 3;     // phase-1 tiling: batch-group, k-slice
  const int jr = tx >> 5, br = tx & 31;  // reduce mapping
  const int b2 = tx & 31, q = tx >> 5;   // phase-2 mapping
  const int ilq = q >> 2, ks = q & 3;

  unsigned gen = 1;
  for (int t = 0; t < 64; ++t) {
    const unsigned short* feed = outs_ext + (size_t)t * 16384;     // slab t
    const unsigned short* hin  = h_ext + (size_t)t * 16384;        // slab t
    unsigned short* hout       = h_ext + (size_t)(t + 1) * 16384;  // slab t+1
    unsigned* hout32           = (unsigned*)hout;

    float acc[8][4];
#pragma unroll
    for (int j = 0; j < 8; ++j)
#pragma unroll
      for (int bi = 0; bi < 4; ++bi) acc[j][bi] = 0.f;

    // ---- phase 1: gates, K=1024, bf16 x/h straight from global (fresh slabs) ----
    for (int ch = 0; ch < 4; ++ch) {
      const unsigned short* src = (ch < 2) ? (feed + ch * 256) : (hin + (ch - 2) * 256);
      float xk0[8], xk1[8], xk2[8], xk3[8];
      bf8_to_f32(src + (size_t)(p * 4 + 0) * 512 + s * 8, xk0);
      bf8_to_f32(src + (size_t)(p * 4 + 1) * 512 + s * 8, xk1);
      bf8_to_f32(src + (size_t)(p * 4 + 2) * 512 + s * 8, xk2);
      bf8_to_f32(src + (size_t)(p * 4 + 3) * 512 + s * 8, xk3);
#pragma unroll
      for (int j = 0; j < 8; ++j) {
        float4 w0 = sw4[j][ch * 64 + s * 2];
        float4 w1 = sw4[j][ch * 64 + s * 2 + 1];
        acc[j][0] += xk0[0]*w0.x + xk0[1]*w0.y + xk0[2]*w0.z + xk0[3]*w0.w
                   + xk0[4]*w1.x + xk0[5]*w1.y + xk0[6]*w1.z + xk0[7]*w1.w;
        acc[j][1] += xk1[0]*w0.x + xk1[1]*w0.y + xk1[2]*w0.z + xk1[3]*w0.w
                   + xk1[4]*w1.x + xk1[5]*w1.y + xk1[6]*w1.z + xk1[7]*w1.w;
        acc[j][2] += xk2[0]*w0.x + xk2[1]*w0.y + xk2[2]*w0.z + xk2[3]*w0.w
                   + xk2[4]*w1.x + xk2[5]*w1.y + xk2[6]*w1.z + xk2[7]*w1.w;
        acc[j][3] += xk3[0]*w0.x + xk3[1]*w0.y + xk3[2]*w0.z + xk3[3]*w0.w
                   + xk3[4]*w1.x + xk3[5]*w1.y + xk3[6]*w1.z + xk3[7]*w1.w;
      }
    }
    // reduce 32 k-slices
#pragma unroll
    for (int j = 0; j < 8; ++j) {
      float4 t4;
      t4.x = acc[j][0]; t4.y = acc[j][1]; t4.z = acc[j][2]; t4.w = acc[j][3];
      *(float4*)(red + s * 256 + j * 32 + p * 4) = t4;
    }
    __syncthreads();
    {
      float sum = 0.f;
#pragma unroll
      for (int sl = 0; sl < 32; ++sl) sum += red[sl * 256 + jr * 32 + br];
      int g = jr >> 1, il = jr & 1;
      int jg = g * 512 + i0 + il;
      sum += xprojT[(size_t)jg * 2048 + t * 32 + br];
      s_g[jr][br] = sum;
    }
    __syncthreads();
    if (tx < 64) {
      int il = tx >> 5, b = tx & 31;
      float gi = s_g[il][b], gf = s_g[2 + il][b], gg = s_g[4 + il][b], go = s_g[6 + il][b];
      float cold = s_c[b][il];
      float si = 1.f / (1.f + __expf(-gi));
      float sf = 1.f / (1.f + __expf(-gf));
      float so = 1.f / (1.f + __expf(-go));
      float cn = sf * cold + si * tanhf(gg);
      s_c[b][il] = cn;
      unsigned hb = f2bf(so * tanhf(cn));
      unsigned other = (unsigned)__shfl_down((int)hb, 32);
      if (tx < 32) {
        unsigned packed = hb | (other << 16);   // low = unit i0, high = i0+1
        __hip_atomic_store(&hout32[b * 256 + bid], packed,
                           __ATOMIC_RELAXED, __HIP_MEMORY_SCOPE_AGENT);
      }
    }
    gbar(bar, gen++);   // h_t complete device-wide

    // ---- phase 2: feed_t slice = tanh(h_t @ W_eff[i0..i0+1]^T + b_eff) ----
    float part = 0.f;
#pragma unroll
    for (int ch = 0; ch < 2; ++ch) {
      const unsigned short* rowp = hout + (size_t)b2 * 512 + ch * 256;
#pragma unroll
      for (int kk = 0; kk < 8; ++kk) {
        float hk[8];
        bf8_to_f32(rowp + ks * 64 + kk * 8, hk);
        float4 w0 = swe4[ilq][ch * 64 + ks * 16 + kk * 2];
        float4 w1 = swe4[ilq][ch * 64 + ks * 16 + kk * 2 + 1];
        part += hk[0]*w0.x + hk[1]*w0.y + hk[2]*w0.z + hk[3]*w0.w
              + hk[4]*w1.x + hk[5]*w1.y + hk[6]*w1.z + hk[7]*w1.w;
      }
    }
    s_r[q][b2] = part;
    __syncthreads();
    if (tx < 64) {
      int il = tx >> 5, b = tx & 31;
      float v = s_r[il * 4 + 0][b] + s_r[il * 4 + 1][b] + s_r[il * 4 + 2][b] + s_r[il * 4 + 3][b]
              + s_be[il];
      unsigned ob = f2bf(tanhf(v));
      unsigned other = (unsigned)__shfl_down((int)ob, 32);
      if (tx < 32) {
        unsigned packed = ob | (other << 16);
        unsigned* o32 = (unsigned*)(outs_ext + (size_t)(t + 1) * 16384);
        __hip_atomic_store(&o32[b * 256 + bid], packed,
                           __ATOMIC_RELAXED, __HIP_MEMORY_SCOPE_AGENT);
      }
    }
    gbar(bar, gen++);   // feed_t complete device-wide
  }
}

// ---- outs bf16 [T][B][H] -> A_bt [(b*T+t)][H] bf16 (pure transpose copy) ----
__global__ __launch_bounds__(256) void k_tr(const unsigned short* __restrict__ outs,
                                            unsigned short* __restrict__ abt) {
  int tid = blockIdx.x * 256 + threadIdx.x;   // 131072 threads
  int idx = tid * 8;
  int m = idx >> 9;        // b*64 + t
  int h0 = idx & 511;
  int b = m >> 6, t = m & 63;
  *(u16x8*)(abt + m * 512 + h0) =
      *(const u16x8*)(outs + (size_t)(t * 32 + b) * 512 + h0);
}

extern "C" void kernel_launch(void* const* d_in, const int* in_sizes, int n_in,
                              void* d_out, int out_size, void* d_ws, size_t ws_size,
                              hipStream_t stream) {
  const int*   seq      = (const int*)d_in[0];
  // d_in[1] = encoder_outputs: attention scores are dead code -> unused
  const float* enc_h    = (const float*)d_in[2];
  const float* enc_c    = (const float*)d_in[3];
  const float* emb      = (const float*)d_in[4];
  const float* W_ih     = (const float*)d_in[5];
  const float* b_ih     = (const float*)d_in[6];
  const float* W_hh     = (const float*)d_in[7];
  const float* b_hh     = (const float*)d_in[8];
  const float* W_inp    = (const float*)d_in[9];
  const float* b_inp    = (const float*)d_in[10];
  const float* W_outp   = (const float*)d_in[11];
  const float* b_outp   = (const float*)d_in[12];
  const float* W_final  = (const float*)d_in[13];
  const float* b_final  = (const float*)d_in[14];
  float* logits = (float*)d_out;

  char* ws = (char*)d_ws;
  size_t off = 0;
  auto alloc = [&](size_t bytes) {
    char* p = ws + off;
    off += (bytes + 255) & ~(size_t)255;
    return p;
  };
  unsigned short* wih_b  = (unsigned short*)alloc((size_t)2048 * 1024 * 2);
  unsigned short* wfin_b = (unsigned short*)alloc((size_t)VV * HH * 2);
  unsigned short* emb_b  = (unsigned short*)alloc((size_t)2048 * 512 * 2);
  float* xprojT = (float*)alloc((size_t)2048 * 2048 * 4);
  float* W_eff  = (float*)alloc((size_t)512 * 512 * 4);
  float* b_eff  = (float*)alloc((size_t)512 * 4);
  unsigned short* h_ext  = (unsigned short*)alloc((size_t)65 * 32 * 512 * 2);
  unsigned short* outs_e = (unsigned short*)alloc((size_t)65 * 32 * 512 * 2);
  unsigned short* abt = (unsigned short*)alloc((size_t)2048 * 512 * 2);
  unsigned* bar = (unsigned*)alloc(4096);

  // per-call init (graph-safe)
  hipMemsetAsync(bar, 0, 4096, stream);
  hipMemsetAsync(outs_e, 0, (size_t)32 * 512 * 2, stream);   // feed for t=0 (bf16 zero)

  hipLaunchKernelGGL(k_cvt_bf16, dim3(1024), dim3(256), 0, stream, W_ih, wih_b, 2048 * 1024 / 8);
  hipLaunchKernelGGL(k_cvt_bf16, dim3(8000), dim3(256), 0, stream, W_final, wfin_b, VV * HH / 8);
  hipLaunchKernelGGL(k_cvt_bf16, dim3(8), dim3(256), 0, stream, enc_h, h_ext, 32 * 512 / 8);
  hipLaunchKernelGGL(k_emb, dim3(512), dim3(256), 0, stream, seq, emb, emb_b);
  hipLaunchKernelGGL(k_weff, dim3(32, 32), dim3(256), 0, stream, W_outp, W_inp, W_eff);
  hipLaunchKernelGGL(k_beff, dim3(2), dim3(256), 0, stream, W_outp, b_inp, b_outp, b_eff);

  // xprojT[j][t*32+b] = W_ih[:, :E] @ emb^T + (b_ih + b_hh) per-row
  hipLaunchKernelGGL(k_gemm, dim3(256), dim3(256), 0, stream,
                     wih_b, 1024, emb_b, 512, xprojT, 2048,
                     (const float*)nullptr, (const float*)nullptr, b_ih, b_hh, 512, 16);

  // persistent recurrence: all 64 steps, 2 all-to-all barriers each
  hipLaunchKernelGGL(k_recur, dim3(256), dim3(256), 0, stream,
                     xprojT, W_ih, W_hh, W_eff, b_eff, enc_c,
                     h_ext, outs_e, bar);

  hipLaunchKernelGGL(k_tr, dim3(512), dim3(256), 0, stream, outs_e + 16384, abt);
  // logits[b*T+t][V] = A_bt @ W_final^T + b_final
  hipLaunchKernelGGL(k_gemm, dim3(4000), dim3(256), 0, stream,
                     abt, 512, wfin_b, 512, logits, 32000,
                     b_final, (const float*)nullptr, (const float*)nullptr, (const float*)nullptr, 512, 16);
}

// Round 6
// 818.100 us; speedup vs baseline: 1.5739x; 1.5739x over previous
//
#include <hip/hip_runtime.h>
#include <hip/hip_bf16.h>

// Dims
#define BB 32
#define TT 64
#define HH 512
#define EE 512
#define VV 32000

typedef float f32x4 __attribute__((ext_vector_type(4)));
typedef float f32x16 __attribute__((ext_vector_type(16)));
typedef __bf16 bf16x8 __attribute__((ext_vector_type(8)));
typedef unsigned short u16x8 __attribute__((ext_vector_type(8)));

static __device__ __forceinline__ unsigned short f2bf(float f) {
  unsigned int u = __builtin_bit_cast(unsigned int, f);
  u += 0x7fffu + ((u >> 16) & 1u);   // RNE; inputs are finite
  return (unsigned short)(u >> 16);
}

// ---- fp32 -> bf16 bulk convert (8 elems/thread) ----
__global__ __launch_bounds__(256) void k_cvt_bf16(const float* __restrict__ in,
                                                  unsigned short* __restrict__ out,
                                                  int n8) {
  int tid = blockIdx.x * 256 + threadIdx.x;
  if (tid >= n8) return;
  int idx = tid * 8;
  float4 a = *(const float4*)(in + idx);
  float4 b = *(const float4*)(in + idx + 4);
  u16x8 o;
  o[0] = f2bf(a.x); o[1] = f2bf(a.y); o[2] = f2bf(a.z); o[3] = f2bf(a.w);
  o[4] = f2bf(b.x); o[5] = f2bf(b.y); o[6] = f2bf(b.z); o[7] = f2bf(b.w);
  *(u16x8*)(out + idx) = o;
}

// ---- embedding gather -> bf16, layout [t*B+b][E] ----
__global__ __launch_bounds__(256) void k_emb(const int* __restrict__ seq,
                                             const float* __restrict__ emb,
                                             unsigned short* __restrict__ out) {
  int tid = blockIdx.x * 256 + threadIdx.x;   // 2048*512/8 = 131072 threads
  int idx = tid * 8;
  int m = idx >> 9;          // t*32 + b
  int e0 = idx & 511;
  int t = m >> 5, b = m & 31;
  int s = seq[b * TT + t];
  const float* src = emb + (size_t)s * EE + e0;
  float4 a = *(const float4*)(src);
  float4 c = *(const float4*)(src + 4);
  u16x8 o;
  o[0] = f2bf(a.x); o[1] = f2bf(a.y); o[2] = f2bf(a.z); o[3] = f2bf(a.w);
  o[4] = f2bf(c.x); o[5] = f2bf(c.y); o[6] = f2bf(c.z); o[7] = f2bf(c.w);
  *(u16x8*)(out + m * EE + e0) = o;
}

// ---- W_eff = W_out[:, :H] @ W_in + W_out[:, H:]  (fp32, one-time) ----
__global__ __launch_bounds__(256) void k_weff(const float* __restrict__ W_out,
                                              const float* __restrict__ W_in,
                                              float* __restrict__ W_eff) {
  __shared__ float sa[16][17], sb[16][17];
  const int t16 = threadIdx.x & 15, ty = threadIdx.x >> 4;
  const int i = blockIdx.y * 16 + ty, m = blockIdx.x * 16 + t16;
  float acc = 0.f;
  for (int k0 = 0; k0 < HH; k0 += 16) {
    sa[ty][t16] = W_out[i * 1024 + k0 + t16];
    sb[ty][t16] = W_in[(k0 + ty) * HH + m];
    __syncthreads();
#pragma unroll
    for (int kk = 0; kk < 16; ++kk) acc += sa[ty][kk] * sb[kk][t16];
    __syncthreads();
  }
  W_eff[i * HH + m] = acc + W_out[i * 1024 + HH + m];
}

__global__ __launch_bounds__(256) void k_beff(const float* __restrict__ W_out,
                                              const float* __restrict__ b_in,
                                              const float* __restrict__ b_out,
                                              float* __restrict__ b_eff) {
  int i = blockIdx.x * 256 + threadIdx.x;
  if (i >= HH) return;
  float acc = b_out[i];
  for (int k = 0; k < HH; ++k) acc += W_out[i * 1024 + k] * b_in[k];
  b_eff[i] = acc;
}

// ---- bf16 MFMA GEMM: C[M][N] = A[M][K] * Bm[N][K]^T (+col biases, +row biases) ----
// 1-D grid, XCD-chunked bijective swizzle for L2 locality.
__global__ __launch_bounds__(256) void k_gemm(const unsigned short* __restrict__ A, int lda,
                                              const unsigned short* __restrict__ Bm, int ldb,
                                              float* __restrict__ C, int ldc,
                                              const float* __restrict__ bias1,
                                              const float* __restrict__ bias2,
                                              const float* __restrict__ biasR1,
                                              const float* __restrict__ biasR2,
                                              int K, int m_panels) {
  __shared__ unsigned short As[128][40];
  __shared__ unsigned short Bs[128][40];
  const int tx = threadIdx.x;
  const int lane = tx & 63, w = tx >> 6;
  const int wrow = (w >> 1) * 64, wcol = (w & 1) * 64;
  const int l15 = lane & 15, lk = lane >> 4;
  const int nb = gridDim.x;
  const int swz = (blockIdx.x & 7) * (nb >> 3) + (blockIdx.x >> 3);
  const int m0 = (swz % m_panels) * 128, n0 = (swz / m_panels) * 128;
  f32x4 acc[4][4] = {};
  for (int k0 = 0; k0 < K; k0 += 32) {
#pragma unroll
    for (int u = 0; u < 2; ++u) {
      int c = u * 256 + tx;               // 512 16B-chunks per matrix
      int row = c >> 2, cc = (c & 3) * 8;
      *(int4*)(&As[row][cc]) = *(const int4*)(A + (size_t)(m0 + row) * lda + k0 + cc);
      *(int4*)(&Bs[row][cc]) = *(const int4*)(Bm + (size_t)(n0 + row) * ldb + k0 + cc);
    }
    __syncthreads();
    bf16x8 av[4], bv[4];
#pragma unroll
    for (int mi = 0; mi < 4; ++mi)
      av[mi] = __builtin_bit_cast(bf16x8, *(const int4*)(&As[wrow + mi * 16 + l15][lk * 8]));
#pragma unroll
    for (int ni = 0; ni < 4; ++ni)
      bv[ni] = __builtin_bit_cast(bf16x8, *(const int4*)(&Bs[wcol + ni * 16 + l15][lk * 8]));
#pragma unroll
    for (int mi = 0; mi < 4; ++mi)
#pragma unroll
      for (int ni = 0; ni < 4; ++ni)
        acc[mi][ni] = __builtin_amdgcn_mfma_f32_16x16x32_bf16(av[mi], bv[ni], acc[mi][ni], 0, 0, 0);
    __syncthreads();
  }
#pragma unroll
  for (int mi = 0; mi < 4; ++mi) {
#pragma unroll
    for (int ni = 0; ni < 4; ++ni) {
      int row = m0 + wrow + mi * 16 + lk * 4;
      int col = n0 + wcol + ni * 16 + l15;
      float bb = 0.f;
      if (bias1) bb += bias1[col];
      if (bias2) bb += bias2[col];
#pragma unroll
      for (int q = 0; q < 4; ++q) {
        float bR = 0.f;
        if (biasR1) bR += biasR1[row + q];
        if (biasR2) bR += biasR2[row + q];
        C[(size_t)(row + q) * ldc + col] = acc[mi][ni][q] + bb + bR;
      }
    }
  }
}

// ---- fence-free grid barrier for 64 blocks ----
// Arrival: one relaxed agent store per block. Exit: wave 0's lanes 0..63 each poll
// one flag (single coalesced 256B line); other waves wait at s_barrier.
// Data is published via relaxed agent atomic stores into never-before-cached slabs,
// so no cache maintenance is needed (r4-validated protocol).
static __device__ __forceinline__ void gbar(unsigned* __restrict__ bar, unsigned gen) {
  __syncthreads();   // all waves drained (compiler emits vmcnt(0) before s_barrier)
  if (threadIdx.x == 0) {
    asm volatile("s_waitcnt vmcnt(0)" ::: "memory");
    __hip_atomic_store(&bar[blockIdx.x], gen, __ATOMIC_RELAXED, __HIP_MEMORY_SCOPE_AGENT);
  }
  if (threadIdx.x < 64) {
    while (__hip_atomic_load(&bar[threadIdx.x], __ATOMIC_RELAXED, __HIP_MEMORY_SCOPE_AGENT) < gen)
      __builtin_amdgcn_s_sleep(1);
  }
  __syncthreads();
  asm volatile("" ::: "memory");   // keep data loads below the spin
}

// ---- persistent MFMA recurrence: 64 blocks x 256 threads (4 waves) ----
// Block bid owns h-units i0=bid*8..+8 (32 gate rows). ALL weights live in VGPRs:
//   wg[16]: gate-weight frags, K=1024 split across 4 waves (16 ktiles each)
//   we[8]:  W_eff frags for unit-group (bid>>2)*32 (redundant x4), K=512 split 4 ways
// Per step: stage bf16 feed/h into swizzled LDS A[32][1024], one 32x32 MFMA tile
// chain per phase, cross-wave K-reduce in LDS, c-state in registers.
__global__ __launch_bounds__(256, 1) void k_recur(
    const float* __restrict__ xprojT,       // [2048][2048] fp32 (incl. b_ih+b_hh)
    const unsigned short* __restrict__ wih_b,  // [2048][1024] bf16
    const unsigned short* __restrict__ whh_b,  // [2048][512] bf16
    const unsigned short* __restrict__ weff_b, // [512][512] bf16
    const float* __restrict__ b_eff,        // [512]
    const float* __restrict__ enc_c,        // [32][512] fp32
    unsigned short* __restrict__ h_ext,     // [65][32][512] bf16; slab 0 = bf16(enc_h)
    unsigned short* __restrict__ outs_ext,  // [65][32][512] bf16; slab 0 zeroed
    unsigned* __restrict__ bar)
{
  __shared__ int4 Abuf4[4096];             // A[32][1024] bf16, XOR-swizzled (64 KB)
  __shared__ float red[4][32][32];         // cross-wave K-partials (16 KB)
  char* Abuf = (char*)Abuf4;

  const int tx = threadIdx.x;
  const int bid = blockIdx.x;
  const int i0 = bid * 8;
  const int w = tx >> 6, l = tx & 63;
  const int jl = l & 31;                   // MFMA operand row (gate-row local / batch)
  const int kh = (l >> 5) * 8;             // k sub-offset within a K16 tile
  const int u = tx >> 5, b = tx & 31;      // activation mapping: unit u (0..7), batch b

  // ---- one-time: weights into registers ----
  bf16x8 wg[16];
  {
    const int jg = (jl >> 3) * 512 + i0 + (jl & 7);   // global gate row
#pragma unroll
    for (int r = 0; r < 16; ++r) {
      int k0 = (w * 16 + r) * 16 + kh;
      const unsigned short* src = (k0 < 512)
          ? wih_b + (size_t)jg * 1024 + 512 + k0      // feed half of W_ih
          : whh_b + (size_t)jg * 512 + (k0 - 512);    // W_hh
      wg[r] = __builtin_bit_cast(bf16x8, *(const int4*)src);
    }
  }
  bf16x8 we[8];
  {
    const int wr = (bid >> 2) * 32 + jl;              // W_eff row (unit group)
#pragma unroll
    for (int r = 0; r < 8; ++r) {
      int k0 = (w * 8 + r) * 16 + kh;
      we[r] = __builtin_bit_cast(bf16x8, *(const int4*)(weff_b + (size_t)wr * 512 + k0));
    }
  }
  float c_reg = enc_c[b * 512 + i0 + u];
  const float be = b_eff[i0 + u];

  // ---- helpers ----
  auto stage = [&](const unsigned short* __restrict__ src, int half) {
#pragma unroll
    for (int rnd = 0; rnd < 8; ++rnd) {
      int id = rnd * 256 + tx;
      int row = id >> 6, c16 = id & 63;
      int4 v = *(const int4*)(src + (size_t)row * 512 + c16 * 8);
      int byte = (row * 2048 + half * 1024 + c16 * 16) ^ ((row & 7) << 4);
      *(int4*)(Abuf + byte) = v;
    }
  };
  auto afrag = [&](int ktile) -> bf16x8 {   // ktile in K16 units over full K=1024
    int byte = (jl * 2048 + ktile * 32 + (l >> 5) * 16) ^ ((jl & 7) << 4);
    return __builtin_bit_cast(bf16x8, *(const int4*)(Abuf + byte));
  };

  // initial stage: feed slab 0 (zeros) + h slab 0 (enc_h)
  stage(outs_ext, 0);
  stage(h_ext, 1);
  __syncthreads();

  unsigned gen = 1;
  for (int t = 0; t < 64; ++t) {
    // ================= phase 1: gates -> h_t =================
    f32x16 acc = {};
#pragma unroll
    for (int r = 0; r < 16; ++r)
      acc = __builtin_amdgcn_mfma_f32_32x32x16_bf16(wg[r], afrag(w * 16 + r), acc, 0, 0, 0);
#pragma unroll
    for (int reg = 0; reg < 16; ++reg) {
      int row = (reg & 3) + 8 * (reg >> 2) + 4 * (l >> 5);
      red[w][row][jl] = acc[reg];
    }
    __syncthreads();
    {
      float g4[4];
#pragma unroll
      for (int g = 0; g < 4; ++g) {
        float s = red[0][g * 8 + u][b] + red[1][g * 8 + u][b]
                + red[2][g * 8 + u][b] + red[3][g * 8 + u][b];
        s += xprojT[(size_t)(g * 512 + i0 + u) * 2048 + t * 32 + b];
        g4[g] = s;
      }
      float si = 1.f / (1.f + __expf(-g4[0]));
      float sf = 1.f / (1.f + __expf(-g4[1]));
      float so = 1.f / (1.f + __expf(-g4[3]));
      float cn = sf * c_reg + si * tanhf(g4[2]);
      c_reg = cn;
      unsigned hb = f2bf(so * tanhf(cn));
      unsigned other = (unsigned)__shfl_down((int)hb, 32);
      if ((u & 1) == 0) {
        unsigned* h32 = (unsigned*)(h_ext + (size_t)(t + 1) * 16384);
        __hip_atomic_store(&h32[b * 256 + bid * 4 + (u >> 1)], hb | (other << 16),
                           __ATOMIC_RELAXED, __HIP_MEMORY_SCOPE_AGENT);
      }
    }
    gbar(bar, gen++);   // h_t visible device-wide

    // ================= phase 2: feed_t = tanh(W_eff h_t + b_eff) =================
    stage(h_ext + (size_t)(t + 1) * 16384, 1);
    __syncthreads();
    f32x16 acc2 = {};
#pragma unroll
    for (int r = 0; r < 8; ++r)
      acc2 = __builtin_amdgcn_mfma_f32_32x32x16_bf16(we[r], afrag(32 + w * 8 + r), acc2, 0, 0, 0);
#pragma unroll
    for (int reg = 0; reg < 16; ++reg) {
      int row = (reg & 3) + 8 * (reg >> 2) + 4 * (l >> 5);
      red[w][row][jl] = acc2[reg];
    }
    __syncthreads();
    {
      int row = (bid & 3) * 8 + u;
      float s = red[0][row][b] + red[1][row][b] + red[2][row][b] + red[3][row][b] + be;
      unsigned ob = f2bf(tanhf(s));
      unsigned other = (unsigned)__shfl_down((int)ob, 32);
      if ((u & 1) == 0) {
        unsigned* o32 = (unsigned*)(outs_ext + (size_t)(t + 1) * 16384);
        __hip_atomic_store(&o32[b * 256 + bid * 4 + (u >> 1)], ob | (other << 16),
                           __ATOMIC_RELAXED, __HIP_MEMORY_SCOPE_AGENT);
      }
    }
    gbar(bar, gen++);   // feed_t visible device-wide

    if (t < 63) {       // stage next step's feed
      stage(outs_ext + (size_t)(t + 1) * 16384, 0);
      __syncthreads();
    }
  }
}

// ---- outs bf16 [T][B][H] -> A_bt [(b*T+t)][H] bf16 (pure transpose copy) ----
__global__ __launch_bounds__(256) void k_tr(const unsigned short* __restrict__ outs,
                                            unsigned short* __restrict__ abt) {
  int tid = blockIdx.x * 256 + threadIdx.x;   // 131072 threads
  int idx = tid * 8;
  int m = idx >> 9;        // b*64 + t
  int h0 = idx & 511;
  int b = m >> 6, t = m & 63;
  *(u16x8*)(abt + m * 512 + h0) =
      *(const u16x8*)(outs + (size_t)(t * 32 + b) * 512 + h0);
}

extern "C" void kernel_launch(void* const* d_in, const int* in_sizes, int n_in,
                              void* d_out, int out_size, void* d_ws, size_t ws_size,
                              hipStream_t stream) {
  const int*   seq      = (const int*)d_in[0];
  // d_in[1] = encoder_outputs: attention scores are dead code -> unused
  const float* enc_h    = (const float*)d_in[2];
  const float* enc_c    = (const float*)d_in[3];
  const float* emb      = (const float*)d_in[4];
  const float* W_ih     = (const float*)d_in[5];
  const float* b_ih     = (const float*)d_in[6];
  const float* W_hh     = (const float*)d_in[7];
  const float* b_hh     = (const float*)d_in[8];
  const float* W_inp    = (const float*)d_in[9];
  const float* b_inp    = (const float*)d_in[10];
  const float* W_outp   = (const float*)d_in[11];
  const float* b_outp   = (const float*)d_in[12];
  const float* W_final  = (const float*)d_in[13];
  const float* b_final  = (const float*)d_in[14];
  float* logits = (float*)d_out;

  char* ws = (char*)d_ws;
  size_t off = 0;
  auto alloc = [&](size_t bytes) {
    char* p = ws + off;
    off += (bytes + 255) & ~(size_t)255;
    return p;
  };
  unsigned short* wih_b  = (unsigned short*)alloc((size_t)2048 * 1024 * 2);
  unsigned short* whh_b  = (unsigned short*)alloc((size_t)2048 * 512 * 2);
  unsigned short* wfin_b = (unsigned short*)alloc((size_t)VV * HH * 2);
  unsigned short* weff_b = (unsigned short*)alloc((size_t)512 * 512 * 2);
  unsigned short* emb_b  = (unsigned short*)alloc((size_t)2048 * 512 * 2);
  float* xprojT = (float*)alloc((size_t)2048 * 2048 * 4);
  float* W_eff  = (float*)alloc((size_t)512 * 512 * 4);
  float* b_eff  = (float*)alloc((size_t)512 * 4);
  unsigned short* h_ext  = (unsigned short*)alloc((size_t)65 * 32 * 512 * 2);
  unsigned short* outs_e = (unsigned short*)alloc((size_t)65 * 32 * 512 * 2);
  unsigned short* abt = (unsigned short*)alloc((size_t)2048 * 512 * 2);
  unsigned* bar = (unsigned*)alloc(4096);

  // per-call init (graph-safe)
  hipMemsetAsync(bar, 0, 4096, stream);
  hipMemsetAsync(outs_e, 0, (size_t)32 * 512 * 2, stream);   // feed for t=0 (bf16 zero)

  hipLaunchKernelGGL(k_cvt_bf16, dim3(1024), dim3(256), 0, stream, W_ih, wih_b, 2048 * 1024 / 8);
  hipLaunchKernelGGL(k_cvt_bf16, dim3(512), dim3(256), 0, stream, W_hh, whh_b, 2048 * 512 / 8);
  hipLaunchKernelGGL(k_cvt_bf16, dim3(8000), dim3(256), 0, stream, W_final, wfin_b, VV * HH / 8);
  hipLaunchKernelGGL(k_cvt_bf16, dim3(8), dim3(256), 0, stream, enc_h, h_ext, 32 * 512 / 8);
  hipLaunchKernelGGL(k_emb, dim3(512), dim3(256), 0, stream, seq, emb, emb_b);
  hipLaunchKernelGGL(k_weff, dim3(32, 32), dim3(256), 0, stream, W_outp, W_inp, W_eff);
  hipLaunchKernelGGL(k_cvt_bf16, dim3(128), dim3(256), 0, stream, W_eff, weff_b, 512 * 512 / 8);
  hipLaunchKernelGGL(k_beff, dim3(2), dim3(256), 0, stream, W_outp, b_inp, b_outp, b_eff);

  // xprojT[j][t*32+b] = W_ih[:, :E] @ emb^T + (b_ih + b_hh) per-row
  hipLaunchKernelGGL(k_gemm, dim3(256), dim3(256), 0, stream,
                     wih_b, 1024, emb_b, 512, xprojT, 2048,
                     (const float*)nullptr, (const float*)nullptr, b_ih, b_hh, 512, 16);

  // persistent MFMA recurrence: 64 blocks, all 64 steps, 2 barriers each
  hipLaunchKernelGGL(k_recur, dim3(64), dim3(256), 0, stream,
                     xprojT, wih_b, whh_b, weff_b, b_eff, enc_c,
                     h_ext, outs_e, bar);

  hipLaunchKernelGGL(k_tr, dim3(512), dim3(256), 0, stream, outs_e + 16384, abt);
  // logits[b*T+t][V] = A_bt @ W_final^T + b_final
  hipLaunchKernelGGL(k_gemm, dim3(4000), dim3(256), 0, stream,
                     abt, 512, wfin_b, 512, logits, 32000,
                     b_final, (const float*)nullptr, (const float*)nullptr, (const float*)nullptr, 512, 16);
}